// Round 1
// baseline (731.937 us; speedup 1.0000x reference)
//
#include <hip/hip_runtime.h>
#include <hip/hip_bf16.h>

// Problem: B=8, C=256, H=W=96, c8=32, pool sizes {1,3,5,7,14} -> 280 positions.
// Restructured: out[b,o] = sum_k aff[b,o,k] * conv3x3(x_1[b], con[k])
//               psp(wq@x+bq) = wq@psp(x)+bq  (pool rows sum to 1)

#define B 8
#define C 256
#define C8 32
#define H 96
#define W 96
#define HW 9216
#define NPOS 280
#define NWBIN 30

// ---------------- pooling: [B,C,96,96] -> [B,C,280] for both x_1 and x ----
__global__ __launch_bounds__(256) void pool_kernel(const float* __restrict__ x1,
                                                   const float* __restrict__ x,
                                                   float* __restrict__ px1,
                                                   float* __restrict__ px) {
    // plane padded to 97 cols: stride 96 would be 0 mod 32 -> 64-way conflicts
    __shared__ float plane[96 * 97];
    __shared__ float rowp[NWBIN * 97];
    const int bi = blockIdx.x;           // 0..4095
    const int which = bi >> 11;          // 0: x_1, 1: x
    const int bc = bi & 2047;
    const float* __restrict__ src = (which ? x : x1) + (size_t)bc * HW;
    float* __restrict__ dst = (which ? px : px1) + (size_t)bc * NPOS;
    const int tid = threadIdx.x;

    for (int idx = tid; idx < HW; idx += 256) {
        int h = idx / 96;
        int w = idx - h * 96;
        plane[h * 97 + w] = src[idx];
    }
    __syncthreads();

    const int SC[5]   = {1, 3, 5, 7, 14};
    const int WOFF[5] = {0, 1, 4, 9, 16};   // cumulative w-bin offsets
    const int POFF[5] = {0, 1, 10, 35, 84}; // cumulative position offsets

    // phase 2: pool along W. tasks = bin*96 + h
    for (int task = tid; task < NWBIN * 96; task += 256) {
        int bin = task / 96;
        int h = task - bin * 96;
        int si;
        if (bin < 1) si = 0; else if (bin < 4) si = 1; else if (bin < 9) si = 2;
        else if (bin < 16) si = 3; else si = 4;
        int s = SC[si];
        int j = bin - WOFF[si];
        int st = (j * 96) / s;
        int en = (96 * (j + 1) + s - 1) / s;
        float sum = 0.f;
        for (int w = st; w < en; ++w) sum += plane[h * 97 + w];
        rowp[bin * 97 + h] = sum * (1.0f / (float)(en - st));
    }
    __syncthreads();

    // phase 3: pool along H -> 280 outputs
    for (int p = tid; p < NPOS; p += 256) {
        int si;
        if (p < 1) si = 0; else if (p < 10) si = 1; else if (p < 35) si = 2;
        else if (p < 84) si = 3; else si = 4;
        int s = SC[si];
        int loc = p - POFF[si];
        int i = loc / s;
        int j = loc - i * s;
        int st = (i * 96) / s;
        int en = (96 * (i + 1) + s - 1) / s;
        int binrow = WOFF[si] + j;
        float sum = 0.f;
        for (int h = st; h < en; ++h) sum += rowp[binrow * 97 + h];
        dst[p] = sum * (1.0f / (float)(en - st));
    }
}

// ---------------- proj: PQ = wq@px1+bq [B,256,280]; PK = wk@px+bk [B,32,280]
__global__ __launch_bounds__(320) void proj_kernel(const float* __restrict__ px1,
                                                   const float* __restrict__ px,
                                                   const float* __restrict__ wq,
                                                   const float* __restrict__ bq,
                                                   const float* __restrict__ wk,
                                                   const float* __restrict__ bk,
                                                   float* __restrict__ PQ,
                                                   float* __restrict__ PK) {
    const int bi = blockIdx.x;   // B * 72
    const int b = bi / 72;
    const int r = bi % 72;
    const int tid = threadIdx.x;
    const float* src;
    const float* wm;
    const float* bias;
    float* dst;
    int o0;
    if (r < 64) {
        o0 = r * 4;
        src = px1 + (size_t)b * C * NPOS;
        wm = wq; bias = bq;
        dst = PQ + ((size_t)b * C + o0) * NPOS;
    } else {
        o0 = (r - 64) * 4;
        src = px + (size_t)b * C * NPOS;
        wm = wk; bias = bk;
        dst = PK + ((size_t)b * C8 + o0) * NPOS;
    }
    if (tid >= NPOS) return;
    float a0 = 0.f, a1 = 0.f, a2 = 0.f, a3 = 0.f;
    for (int c = 0; c < C; ++c) {
        float xv = src[c * NPOS + tid];
        a0 += wm[(o0 + 0) * C + c] * xv;
        a1 += wm[(o0 + 1) * C + c] * xv;
        a2 += wm[(o0 + 2) * C + c] * xv;
        a3 += wm[(o0 + 3) * C + c] * xv;
    }
    dst[0 * NPOS + tid] = a0 + bias[o0 + 0];
    dst[1 * NPOS + tid] = a1 + bias[o0 + 1];
    dst[2 * NPOS + tid] = a2 + bias[o0 + 2];
    dst[3 * NPOS + tid] = a3 + bias[o0 + 3];
}

// ---------------- aff[b,o,k] = sigmoid(PQ[b,o,:] . PK[b,k,:]) --------------
__global__ __launch_bounds__(256) void aff_kernel(const float* __restrict__ PQ,
                                                  const float* __restrict__ PK,
                                                  float* __restrict__ affw) {
    __shared__ float pk[NPOS];
    const int b = blockIdx.x >> 5;
    const int k = blockIdx.x & 31;
    const int tid = threadIdx.x;
    const float* __restrict__ pkr = PK + ((size_t)b * C8 + k) * NPOS;
    if (tid < 256) pk[tid] = pkr[tid];
    if (tid < NPOS - 256) pk[tid + 256] = pkr[tid + 256];
    __syncthreads();
    const float4* __restrict__ q4 = (const float4*)(PQ + ((size_t)b * C + tid) * NPOS);
    const float4* __restrict__ p4 = (const float4*)pk;
    float acc = 0.f;
    #pragma unroll 10
    for (int i = 0; i < NPOS / 4; ++i) {
        float4 a = q4[i];
        float4 c = p4[i];
        acc += a.x * c.x + a.y * c.y + a.z * c.z + a.w * c.w;
    }
    float s = 1.0f / (1.0f + __expf(-acc));
    affw[((size_t)b * C + tid) * C8 + k] = s;
}

// ---------------- transpose con[k,c,3,3] -> con_t[c,k,9] -------------------
__global__ __launch_bounds__(256) void tcon_kernel(const float* __restrict__ con,
                                                   float* __restrict__ con_t) {
    int idx = blockIdx.x * 256 + threadIdx.x;   // 32*256*9 = 73728
    if (idx >= C8 * C * 9) return;
    int k = idx / (C * 9);
    int rem = idx - k * (C * 9);
    int c = rem / 9;
    int t = rem - c * 9;
    con_t[(c * C8 + k) * 9 + t] = con[idx];
}

// ---------------- Y partial conv: Yp[chunk,b,k,H,W], chunk over c ----------
// tile 16(y) x 32(x), thread = 2 horizontal pixels, 32 k-accumulators.
__global__ __launch_bounds__(256) void yconv_kernel(const float* __restrict__ x1,
                                                    const float* __restrict__ con_t,
                                                    float* __restrict__ Yp) {
    __shared__ float xs[18 * 37];   // 18 rows x 34 cols, padded stride 37
    const int bi = blockIdx.x;      // 8 b * 18 tiles * 4 chunks = 576
    const int chunk = bi & 3;
    const int t = (bi >> 2) % 18;
    const int b = bi / 72;
    const int tiley = t / 3, tilex = t % 3;
    const int base_y = tiley * 16, base_x = tilex * 32;
    const int tid = threadIdx.x;
    const int ty = tid >> 4;        // 0..15
    const int x0 = (tid & 15) * 2;  // 0..30

    float acc[C8][2];
    #pragma unroll
    for (int k = 0; k < C8; ++k) { acc[k][0] = 0.f; acc[k][1] = 0.f; }

    const int c0 = chunk * 64;
    for (int ci = 0; ci < 64; ++ci) {
        const int c = c0 + ci;
        const float* __restrict__ xp = x1 + ((size_t)(b * C + c)) * HW;
        __syncthreads();
        for (int idx = tid; idx < 18 * 34; idx += 256) {
            int r = idx / 34;
            int col = idx - r * 34;
            int gy = base_y + r - 1;
            int gx = base_x + col - 1;
            float v = 0.f;
            if (gy >= 0 && gy < 96 && gx >= 0 && gx < 96) v = xp[gy * 96 + gx];
            xs[r * 37 + col] = v;
        }
        __syncthreads();

        float v[3][4];
        #pragma unroll
        for (int dy = 0; dy < 3; ++dy)
            #pragma unroll
            for (int dx = 0; dx < 4; ++dx)
                v[dy][dx] = xs[(ty + dy) * 37 + x0 + dx];

        const float* __restrict__ wp = con_t + (size_t)c * (C8 * 9);
        #pragma unroll
        for (int k = 0; k < C8; ++k) {
            const float* wk9 = wp + k * 9;   // wave-uniform -> s_load
            float a0 = acc[k][0], a1 = acc[k][1];
            #pragma unroll
            for (int dy = 0; dy < 3; ++dy) {
                float w0 = wk9[dy * 3 + 0];
                float w1 = wk9[dy * 3 + 1];
                float w2 = wk9[dy * 3 + 2];
                a0 += w0 * v[dy][0] + w1 * v[dy][1] + w2 * v[dy][2];
                a1 += w0 * v[dy][1] + w1 * v[dy][2] + w2 * v[dy][3];
            }
            acc[k][0] = a0; acc[k][1] = a1;
        }
    }

    const int y = base_y + ty;
    const int x = base_x + x0;
    #pragma unroll
    for (int k = 0; k < C8; ++k) {
        size_t base = (((size_t)chunk * B + b) * C8 + k) * HW + y * 96 + x;
        Yp[base + 0] = acc[k][0];
        Yp[base + 1] = acc[k][1];
    }
}

// ---------------- mix: out[b,o,p] = sum_k aff[b,o,k] * sum_chunk Yp --------
__global__ __launch_bounds__(128) void mix_kernel(const float* __restrict__ Yp,
                                                  const float* __restrict__ affw,
                                                  float* __restrict__ out) {
    const int bi = blockIdx.x;   // 8 * 72 = 576
    const int b = bi / 72;
    const int t = bi % 72;
    const int px = t * 128 + threadIdx.x;

    float y[C8];
    #pragma unroll
    for (int k = 0; k < C8; ++k) y[k] = 0.f;
    #pragma unroll
    for (int chunk = 0; chunk < 4; ++chunk) {
        #pragma unroll
        for (int k = 0; k < C8; ++k)
            y[k] += Yp[(((size_t)chunk * B + b) * C8 + k) * HW + px];
    }

    const float* __restrict__ ab = affw + (size_t)b * C * C8;
    for (int o = 0; o < C; ++o) {
        const float* ar = ab + o * C8;   // wave-uniform -> s_load
        float acc = 0.f;
        #pragma unroll
        for (int k = 0; k < C8; ++k) acc += ar[k] * y[k];
        out[((size_t)b * C + o) * HW + px] = acc;
    }
}

extern "C" void kernel_launch(void* const* d_in, const int* in_sizes, int n_in,
                              void* d_out, int out_size, void* d_ws, size_t ws_size,
                              hipStream_t stream) {
    const float* x1  = (const float*)d_in[0];
    const float* x   = (const float*)d_in[1];
    const float* wq  = (const float*)d_in[2];
    const float* bq  = (const float*)d_in[3];
    const float* wk  = (const float*)d_in[4];
    const float* bk  = (const float*)d_in[5];
    const float* con = (const float*)d_in[6];
    float* out = (float*)d_out;

    float* ws    = (float*)d_ws;
    float* px1   = ws;                 // B*C*280        = 573440
    float* px    = ws + 573440;        // B*C*280        = 573440
    float* PQ    = ws + 1146880;       // B*256*280      = 573440
    float* PK    = ws + 1720320;       // B*32*280       = 71680
    float* affw  = ws + 1792000;       // B*256*32       = 65536
    float* con_t = ws + 1857536;       // 256*32*9       = 73728
    float* Yp    = ws + 1931264;       // 4*8*32*9216    = 9437184  (total ~45.5 MB)

    tcon_kernel<<<288, 256, 0, stream>>>(con, con_t);
    pool_kernel<<<4096, 256, 0, stream>>>(x1, x, px1, px);
    proj_kernel<<<B * 72, 320, 0, stream>>>(px1, px, wq, bq, wk, bk, PQ, PK);
    aff_kernel<<<B * 32, 256, 0, stream>>>(PQ, PK, affw);
    yconv_kernel<<<576, 256, 0, stream>>>(x1, con_t, Yp);
    mix_kernel<<<576, 128, 0, stream>>>(Yp, affw, out);
}

// Round 2
// 642.528 us; speedup vs baseline: 1.1392x; 1.1392x over previous
//
#include <hip/hip_runtime.h>
#include <hip/hip_bf16.h>

// Problem: B=8, C=256, H=W=96, c8=32, pool sizes {1,3,5,7,14} -> 280 positions.
// Restructured: out[b,o] = sum_k aff[b,o,k] * conv3x3(x_1[b], con[k])
//               psp(wq@x+bq) = wq@psp(x)+bq  (pool rows sum to 1)

#define B 8
#define C 256
#define C8 32
#define H 96
#define W 96
#define HW 9216
#define NPOS 280
#define NWBIN 30

// ---------------- pooling: [B,C,96,96] -> [B,C,280] for both x_1 and x ----
__global__ __launch_bounds__(256) void pool_kernel(const float* __restrict__ x1,
                                                   const float* __restrict__ x,
                                                   float* __restrict__ px1,
                                                   float* __restrict__ px) {
    __shared__ float plane[96 * 97];
    __shared__ float rowp[NWBIN * 97];
    const int bi = blockIdx.x;           // 0..4095
    const int which = bi >> 11;          // 0: x_1, 1: x
    const int bc = bi & 2047;
    const float* __restrict__ src = (which ? x : x1) + (size_t)bc * HW;
    float* __restrict__ dst = (which ? px : px1) + (size_t)bc * NPOS;
    const int tid = threadIdx.x;

    for (int idx = tid; idx < HW; idx += 256) {
        int h = idx / 96;
        int w = idx - h * 96;
        plane[h * 97 + w] = src[idx];
    }
    __syncthreads();

    const int SC[5]   = {1, 3, 5, 7, 14};
    const int WOFF[5] = {0, 1, 4, 9, 16};
    const int POFF[5] = {0, 1, 10, 35, 84};

    for (int task = tid; task < NWBIN * 96; task += 256) {
        int bin = task / 96;
        int h = task - bin * 96;
        int si;
        if (bin < 1) si = 0; else if (bin < 4) si = 1; else if (bin < 9) si = 2;
        else if (bin < 16) si = 3; else si = 4;
        int s = SC[si];
        int j = bin - WOFF[si];
        int st = (j * 96) / s;
        int en = (96 * (j + 1) + s - 1) / s;
        float sum = 0.f;
        for (int w = st; w < en; ++w) sum += plane[h * 97 + w];
        rowp[bin * 97 + h] = sum * (1.0f / (float)(en - st));
    }
    __syncthreads();

    for (int p = tid; p < NPOS; p += 256) {
        int si;
        if (p < 1) si = 0; else if (p < 10) si = 1; else if (p < 35) si = 2;
        else if (p < 84) si = 3; else si = 4;
        int s = SC[si];
        int loc = p - POFF[si];
        int i = loc / s;
        int j = loc - i * s;
        int st = (i * 96) / s;
        int en = (96 * (i + 1) + s - 1) / s;
        int binrow = WOFF[si] + j;
        float sum = 0.f;
        for (int h = st; h < en; ++h) sum += rowp[binrow * 97 + h];
        dst[p] = sum * (1.0f / (float)(en - st));
    }
}

// ---------------- proj: PQ = wq@px1+bq [B,256,280]; PK = wk@px+bk [B,32,280]
__global__ __launch_bounds__(320) void proj_kernel(const float* __restrict__ px1,
                                                   const float* __restrict__ px,
                                                   const float* __restrict__ wq,
                                                   const float* __restrict__ bq,
                                                   const float* __restrict__ wk,
                                                   const float* __restrict__ bk,
                                                   float* __restrict__ PQ,
                                                   float* __restrict__ PK) {
    const int bi = blockIdx.x;   // B * 72
    const int b = bi / 72;
    const int r = bi % 72;
    const int tid = threadIdx.x;
    const float* src;
    const float* wm;
    const float* bias;
    float* dst;
    int o0;
    if (r < 64) {
        o0 = r * 4;
        src = px1 + (size_t)b * C * NPOS;
        wm = wq; bias = bq;
        dst = PQ + ((size_t)b * C + o0) * NPOS;
    } else {
        o0 = (r - 64) * 4;
        src = px + (size_t)b * C * NPOS;
        wm = wk; bias = bk;
        dst = PK + ((size_t)b * C8 + o0) * NPOS;
    }
    if (tid >= NPOS) return;
    float a0 = 0.f, a1 = 0.f, a2 = 0.f, a3 = 0.f;
    for (int c = 0; c < C; ++c) {
        float xv = src[c * NPOS + tid];
        a0 += wm[(o0 + 0) * C + c] * xv;
        a1 += wm[(o0 + 1) * C + c] * xv;
        a2 += wm[(o0 + 2) * C + c] * xv;
        a3 += wm[(o0 + 3) * C + c] * xv;
    }
    dst[0 * NPOS + tid] = a0 + bias[o0 + 0];
    dst[1 * NPOS + tid] = a1 + bias[o0 + 1];
    dst[2 * NPOS + tid] = a2 + bias[o0 + 2];
    dst[3 * NPOS + tid] = a3 + bias[o0 + 3];
}

// ---------------- aff[b,o,k] = sigmoid(PQ[b,o,:] . PK[b,k,:]) --------------
__global__ __launch_bounds__(256) void aff_kernel(const float* __restrict__ PQ,
                                                  const float* __restrict__ PK,
                                                  float* __restrict__ affw) {
    __shared__ float pk[NPOS];
    const int b = blockIdx.x >> 5;
    const int k = blockIdx.x & 31;
    const int tid = threadIdx.x;
    const float* __restrict__ pkr = PK + ((size_t)b * C8 + k) * NPOS;
    if (tid < 256) pk[tid] = pkr[tid];
    if (tid < NPOS - 256) pk[tid + 256] = pkr[tid + 256];
    __syncthreads();
    const float4* __restrict__ q4 = (const float4*)(PQ + ((size_t)b * C + tid) * NPOS);
    const float4* __restrict__ p4 = (const float4*)pk;
    float acc = 0.f;
    #pragma unroll 10
    for (int i = 0; i < NPOS / 4; ++i) {
        float4 a = q4[i];
        float4 c = p4[i];
        acc += a.x * c.x + a.y * c.y + a.z * c.z + a.w * c.w;
    }
    float s = 1.0f / (1.0f + __expf(-acc));
    affw[((size_t)b * C + tid) * C8 + k] = s;
}

// ---------------- transpose con[k,c,3,3] -> con_t[c,k,9] -------------------
__global__ __launch_bounds__(256) void tcon_kernel(const float* __restrict__ con,
                                                   float* __restrict__ con_t) {
    int idx = blockIdx.x * 256 + threadIdx.x;   // 32*256*9 = 73728
    if (idx >= C8 * C * 9) return;
    int k = idx / (C * 9);
    int rem = idx - k * (C * 9);
    int c = rem / 9;
    int t = rem - c * 9;
    con_t[(c * C8 + k) * 9 + t] = con[idx];
}

// ---------------- Y partial conv: Yp[chunk,b,k,H,W], chunk over c ----------
// tile 8(y) x 32(x), thread = 1 pixel, 32 k-accumulators.
// grid = 8 b * 36 tiles * 4 chunks = 1152 blocks (~18 waves/CU)
__global__ __launch_bounds__(256) void yconv_kernel(const float* __restrict__ x1,
                                                    const float* __restrict__ con_t,
                                                    float* __restrict__ Yp) {
    __shared__ float xs[10 * 37];   // 10 rows x 34 cols, padded stride 37
    const int bi = blockIdx.x;      // 1152
    const int chunk = bi & 3;
    const int t = (bi >> 2) % 36;
    const int b = bi / 144;
    const int tiley = t / 3, tilex = t % 3;
    const int base_y = tiley * 8, base_x = tilex * 32;
    const int tid = threadIdx.x;
    const int ty = tid >> 5;        // 0..7
    const int tx = tid & 31;        // 0..31

    float acc[C8];
    #pragma unroll
    for (int k = 0; k < C8; ++k) acc[k] = 0.f;

    const int c0 = chunk * 64;
    for (int ci = 0; ci < 64; ++ci) {
        const int c = c0 + ci;
        const float* __restrict__ xp = x1 + ((size_t)(b * C + c)) * HW;
        __syncthreads();
        for (int idx = tid; idx < 10 * 34; idx += 256) {
            int r = idx / 34;
            int col = idx - r * 34;
            int gy = base_y + r - 1;
            int gx = base_x + col - 1;
            float v = 0.f;
            if (gy >= 0 && gy < 96 && gx >= 0 && gx < 96) v = xp[gy * 96 + gx];
            xs[r * 37 + col] = v;
        }
        __syncthreads();

        // 3x3 window for this thread's pixel (2-way LDS aliasing only -> free)
        float v[3][3];
        #pragma unroll
        for (int dy = 0; dy < 3; ++dy)
            #pragma unroll
            for (int dx = 0; dx < 3; ++dx)
                v[dy][dx] = xs[(ty + dy) * 37 + tx + dx];

        const float* __restrict__ wp = con_t + (size_t)c * (C8 * 9);
        #pragma unroll
        for (int k = 0; k < C8; ++k) {
            const float* wk9 = wp + k * 9;   // wave-uniform -> s_load
            float a = acc[k];
            #pragma unroll
            for (int dy = 0; dy < 3; ++dy) {
                a += wk9[dy * 3 + 0] * v[dy][0];
                a += wk9[dy * 3 + 1] * v[dy][1];
                a += wk9[dy * 3 + 2] * v[dy][2];
            }
            acc[k] = a;
        }
    }

    const int y = base_y + ty;
    const int x = base_x + tx;
    #pragma unroll
    for (int k = 0; k < C8; ++k)
        Yp[(((size_t)chunk * B + b) * C8 + k) * HW + y * 96 + x] = acc[k];
}

// ---------------- mix: out[b,o,p] = sum_k aff[b,o,k] * sum_chunk Yp --------
// grid = 8 b * 36 px-tiles(256) * 2 o-groups(128) = 576 blocks, 256 thr
__global__ __launch_bounds__(256) void mix_kernel(const float* __restrict__ Yp,
                                                  const float* __restrict__ affw,
                                                  float* __restrict__ out) {
    const int bi = blockIdx.x;   // 576
    const int b = bi / 72;
    const int rem = bi % 72;
    const int ptile = rem % 36;
    const int og = rem / 36;     // 0..1
    const int px = ptile * 256 + threadIdx.x;

    float y[C8];
    #pragma unroll
    for (int k = 0; k < C8; ++k) y[k] = 0.f;
    #pragma unroll
    for (int chunk = 0; chunk < 4; ++chunk) {
        #pragma unroll
        for (int k = 0; k < C8; ++k)
            y[k] += Yp[(((size_t)chunk * B + b) * C8 + k) * HW + px];
    }

    const float* __restrict__ ab = affw + (size_t)b * C * C8;
    const int o0 = og * 128;
    for (int o = o0; o < o0 + 128; ++o) {
        const float* ar = ab + o * C8;   // wave-uniform -> s_load
        float acc = 0.f;
        #pragma unroll
        for (int k = 0; k < C8; ++k) acc += ar[k] * y[k];
        out[((size_t)b * C + o) * HW + px] = acc;
    }
}

extern "C" void kernel_launch(void* const* d_in, const int* in_sizes, int n_in,
                              void* d_out, int out_size, void* d_ws, size_t ws_size,
                              hipStream_t stream) {
    const float* x1  = (const float*)d_in[0];
    const float* x   = (const float*)d_in[1];
    const float* wq  = (const float*)d_in[2];
    const float* bq  = (const float*)d_in[3];
    const float* wk  = (const float*)d_in[4];
    const float* bk  = (const float*)d_in[5];
    const float* con = (const float*)d_in[6];
    float* out = (float*)d_out;

    float* ws    = (float*)d_ws;
    float* px1   = ws;                 // B*C*280        = 573440
    float* px    = ws + 573440;        // B*C*280        = 573440
    float* PQ    = ws + 1146880;       // B*256*280      = 573440
    float* PK    = ws + 1720320;       // B*32*280       = 71680
    float* affw  = ws + 1792000;       // B*256*32       = 65536
    float* con_t = ws + 1857536;       // 256*32*9       = 73728
    float* Yp    = ws + 1931264;       // 4*8*32*9216    = 9437184  (total ~45.5 MB)

    tcon_kernel<<<288, 256, 0, stream>>>(con, con_t);
    pool_kernel<<<4096, 256, 0, stream>>>(x1, x, px1, px);
    proj_kernel<<<B * 72, 320, 0, stream>>>(px1, px, wq, bq, wk, bk, PQ, PK);
    aff_kernel<<<B * 32, 256, 0, stream>>>(PQ, PK, affw);
    yconv_kernel<<<1152, 256, 0, stream>>>(x1, con_t, Yp);
    mix_kernel<<<576, 256, 0, stream>>>(Yp, affw, out);
}

// Round 3
// 562.135 us; speedup vs baseline: 1.3021x; 1.1430x over previous
//
#include <hip/hip_runtime.h>
#include <hip/hip_bf16.h>

// Problem: B=8, C=256, H=W=96, c8=32, pool sizes {1,3,5,7,14} -> 280 positions.
// Restructured: out[b,o] = sum_k aff[b,o,k] * conv3x3(x_1[b], con[k])
//               psp(wq@x+bq) = wq@psp(x)+bq  (pool rows sum to 1)
// yconv as implicit-GEMM bf16 MFMA: Y[b](32x9216) = W(32x2304) @ im2col(x1[b])

#define B 8
#define C 256
#define C8 32
#define H 96
#define W 96
#define HW 9216
#define NPOS 280
#define NWBIN 30

typedef __attribute__((ext_vector_type(8))) short short8;
typedef __attribute__((ext_vector_type(4))) float float4v;

static __device__ __forceinline__ unsigned short f2bf(float f) {
    unsigned u = __float_as_uint(f);
    unsigned r = (u + 0x7FFF + ((u >> 16) & 1)) >> 16;   // RNE
    return (unsigned short)r;
}

// ---------------- pooling: [B,C,96,96] -> [B,C,280] for both x_1 and x ----
__global__ __launch_bounds__(256) void pool_kernel(const float* __restrict__ x1,
                                                   const float* __restrict__ x,
                                                   float* __restrict__ px1,
                                                   float* __restrict__ px) {
    __shared__ float plane[96 * 97];
    __shared__ float rowp[NWBIN * 97];
    const int bi = blockIdx.x;           // 0..4095
    const int which = bi >> 11;          // 0: x_1, 1: x
    const int bc = bi & 2047;
    const float* __restrict__ src = (which ? x : x1) + (size_t)bc * HW;
    float* __restrict__ dst = (which ? px : px1) + (size_t)bc * NPOS;
    const int tid = threadIdx.x;

    for (int idx = tid; idx < HW; idx += 256) {
        int h = idx / 96;
        int w = idx - h * 96;
        plane[h * 97 + w] = src[idx];
    }
    __syncthreads();

    const int SC[5]   = {1, 3, 5, 7, 14};
    const int WOFF[5] = {0, 1, 4, 9, 16};
    const int POFF[5] = {0, 1, 10, 35, 84};

    for (int task = tid; task < NWBIN * 96; task += 256) {
        int bin = task / 96;
        int h = task - bin * 96;
        int si;
        if (bin < 1) si = 0; else if (bin < 4) si = 1; else if (bin < 9) si = 2;
        else if (bin < 16) si = 3; else si = 4;
        int s = SC[si];
        int j = bin - WOFF[si];
        int st = (j * 96) / s;
        int en = (96 * (j + 1) + s - 1) / s;
        float sum = 0.f;
        for (int w = st; w < en; ++w) sum += plane[h * 97 + w];
        rowp[bin * 97 + h] = sum * (1.0f / (float)(en - st));
    }
    __syncthreads();

    for (int p = tid; p < NPOS; p += 256) {
        int si;
        if (p < 1) si = 0; else if (p < 10) si = 1; else if (p < 35) si = 2;
        else if (p < 84) si = 3; else si = 4;
        int s = SC[si];
        int loc = p - POFF[si];
        int i = loc / s;
        int j = loc - i * s;
        int st = (i * 96) / s;
        int en = (96 * (i + 1) + s - 1) / s;
        int binrow = WOFF[si] + j;
        float sum = 0.f;
        for (int h = st; h < en; ++h) sum += rowp[binrow * 97 + h];
        dst[p] = sum * (1.0f / (float)(en - st));
    }
}

// ---------------- proj: PQ = wq@px1+bq [B,256,280]; PK = wk@px+bk [B,32,280]
__global__ __launch_bounds__(320) void proj_kernel(const float* __restrict__ px1,
                                                   const float* __restrict__ px,
                                                   const float* __restrict__ wq,
                                                   const float* __restrict__ bq,
                                                   const float* __restrict__ wk,
                                                   const float* __restrict__ bk,
                                                   float* __restrict__ PQ,
                                                   float* __restrict__ PK) {
    const int bi = blockIdx.x;   // B * 72
    const int b = bi / 72;
    const int r = bi % 72;
    const int tid = threadIdx.x;
    const float* src;
    const float* wm;
    const float* bias;
    float* dst;
    int o0;
    if (r < 64) {
        o0 = r * 4;
        src = px1 + (size_t)b * C * NPOS;
        wm = wq; bias = bq;
        dst = PQ + ((size_t)b * C + o0) * NPOS;
    } else {
        o0 = (r - 64) * 4;
        src = px + (size_t)b * C * NPOS;
        wm = wk; bias = bk;
        dst = PK + ((size_t)b * C8 + o0) * NPOS;
    }
    if (tid >= NPOS) return;
    float a0 = 0.f, a1 = 0.f, a2 = 0.f, a3 = 0.f;
    for (int c = 0; c < C; ++c) {
        float xv = src[c * NPOS + tid];
        a0 += wm[(o0 + 0) * C + c] * xv;
        a1 += wm[(o0 + 1) * C + c] * xv;
        a2 += wm[(o0 + 2) * C + c] * xv;
        a3 += wm[(o0 + 3) * C + c] * xv;
    }
    dst[0 * NPOS + tid] = a0 + bias[o0 + 0];
    dst[1 * NPOS + tid] = a1 + bias[o0 + 1];
    dst[2 * NPOS + tid] = a2 + bias[o0 + 2];
    dst[3 * NPOS + tid] = a3 + bias[o0 + 3];
}

// ---------------- aff[b,o,k] = sigmoid(PQ[b,o,:] . PK[b,k,:]) --------------
__global__ __launch_bounds__(256) void aff_kernel(const float* __restrict__ PQ,
                                                  const float* __restrict__ PK,
                                                  float* __restrict__ affw) {
    __shared__ float pk[NPOS];
    const int b = blockIdx.x >> 5;
    const int k = blockIdx.x & 31;
    const int tid = threadIdx.x;
    const float* __restrict__ pkr = PK + ((size_t)b * C8 + k) * NPOS;
    if (tid < 256) pk[tid] = pkr[tid];
    if (tid < NPOS - 256) pk[tid + 256] = pkr[tid + 256];
    __syncthreads();
    const float4* __restrict__ q4 = (const float4*)(PQ + ((size_t)b * C + tid) * NPOS);
    const float4* __restrict__ p4 = (const float4*)pk;
    float acc = 0.f;
    #pragma unroll 10
    for (int i = 0; i < NPOS / 4; ++i) {
        float4 a = q4[i];
        float4 c = p4[i];
        acc += a.x * c.x + a.y * c.y + a.z * c.z + a.w * c.w;
    }
    float s = 1.0f / (1.0f + __expf(-acc));
    affw[((size_t)b * C + tid) * C8 + k] = s;
}

// ---------------- prep: con[k,c,3,3] -> Aswz in MFMA A-fragment order ------
// K-order: kidx = (pos*8 + cg)*32 + ci  (pos = dy*3+dx, 32-channel groups)
// Aswz[((s*2 + mt)*64 + lane)*8 + j], s = pos*8+cg:
//   A[m=lane&15][k=(lane>>4)*8+j],  m -> k_out = mt*16+m, k -> c = cg*32+k
__global__ __launch_bounds__(256) void aswz_kernel(const float* __restrict__ con,
                                                   unsigned short* __restrict__ aswz) {
    int idx = blockIdx.x * 256 + threadIdx.x;   // 72*2*64*8 = 73728
    if (idx >= 73728) return;
    int j = idx & 7;
    int lane = (idx >> 3) & 63;
    int mt = (idx >> 9) & 1;
    int s = idx >> 10;          // 0..71
    int pos = s >> 3;
    int cg = s & 7;
    int m = lane & 15, quad = lane >> 4;
    int ko = mt * 16 + m;
    int c = cg * 32 + quad * 8 + j;
    int dy = pos / 3, dx = pos - dy * 3;
    float v = con[((ko * C + c) * 3 + dy) * 3 + dx];
    aswz[idx] = f2bf(v);
}

// ---------------- Y = W @ im2col(x1) via MFMA --------------------------------
// tile: 6 rows x 48 cols = 288 px = 18 N-tiles; 3 waves x 6 N-tiles.
// grid = 8 b * 16 ytiles * 2 xtiles = 256 blocks.
__global__ __launch_bounds__(192) void yconv_mfma(const float* __restrict__ x1,
                                                  const unsigned short* __restrict__ aswz,
                                                  float* __restrict__ Y) {
    __shared__ unsigned short xsl[8 * 50 * 40];   // [row][col][ch pad 40] bf16, 32000 B
    __shared__ unsigned short asl[9 * 1024];      // [pos][mt][lane][j] bf16, 18432 B
    const int bi = blockIdx.x;
    const int b = bi >> 5;
    const int tile = bi & 31;
    const int tiley = tile >> 1, tilex = tile & 1;
    const int tid = threadIdx.x;
    const int wid = tid / 64;
    const int lane = tid & 63;
    const int n = lane & 15, quad = lane >> 4;

    float4v acc[2][6];
    #pragma unroll
    for (int mt = 0; mt < 2; ++mt)
        #pragma unroll
        for (int t = 0; t < 6; ++t)
            acc[mt][t] = (float4v){0.f, 0.f, 0.f, 0.f};

    int baseb[6];
    #pragma unroll
    for (int t = 0; t < 6; ++t) {
        int tt = wid * 6 + t;
        int rt = tt / 3;
        int xb = (tt % 3) * 16;
        baseb[t] = (rt * 50 + xb + n) * 40 + quad * 8;
    }

    const unsigned int* __restrict__ aw = (const unsigned int*)aswz;
    unsigned int* aslw = (unsigned int*)asl;

    for (int cg = 0; cg < 8; ++cg) {
        __syncthreads();
        // stage X slab: 32 ch x 8 rows x 50 cols, fp32 -> bf16
        for (int idx = tid; idx < 12800; idx += 192) {
            int ci = idx / 400;
            int rem = idx - ci * 400;
            int r = rem / 50;
            int col = rem - r * 50;
            int gy = tiley * 6 + r - 1;
            int gx = tilex * 48 + col - 1;
            float v = 0.f;
            if ((unsigned)gy < 96u && (unsigned)gx < 96u)
                v = x1[((size_t)(b * C + cg * 32 + ci)) * HW + gy * 96 + gx];
            xsl[(r * 50 + col) * 40 + ci] = f2bf(v);
        }
        // stage A slab for this cg: 9 pos x 1024 bf16 (already fragment-ordered)
        for (int t = tid; t < 4608; t += 192) {
            int pos = t >> 9;
            int off = t & 511;
            aslw[t] = aw[(pos * 8 + cg) * 512 + off];
        }
        __syncthreads();

        #pragma unroll
        for (int pos = 0; pos < 9; ++pos) {
            const int dy = pos / 3, dx = pos - (pos / 3) * 3;
            short8 a0 = *(const short8*)&asl[pos * 1024 + lane * 8];
            short8 a1 = *(const short8*)&asl[pos * 1024 + 512 + lane * 8];
            const int d = (dy * 50 + dx) * 40;
            #pragma unroll
            for (int t = 0; t < 6; ++t) {
                short8 bf = *(const short8*)&xsl[baseb[t] + d];
                acc[0][t] = __builtin_amdgcn_mfma_f32_16x16x32_bf16(a0, bf, acc[0][t], 0, 0, 0);
                acc[1][t] = __builtin_amdgcn_mfma_f32_16x16x32_bf16(a1, bf, acc[1][t], 0, 0, 0);
            }
        }
    }

    // store: D col=lane&15 -> pixel, row=quad*4+reg -> k_out within M-tile
    #pragma unroll
    for (int mt = 0; mt < 2; ++mt) {
        #pragma unroll
        for (int t = 0; t < 6; ++t) {
            int tt = wid * 6 + t;
            int rt = tt / 3;
            int xb = (tt % 3) * 16;
            int gy = tiley * 6 + rt;
            int gx = tilex * 48 + xb + n;
            #pragma unroll
            for (int reg = 0; reg < 4; ++reg) {
                int ko = mt * 16 + quad * 4 + reg;
                Y[((size_t)(b * C8 + ko)) * HW + gy * 96 + gx] = acc[mt][t][reg];
            }
        }
    }
}

// ---------------- mix: out[b,o,p] = sum_k aff[b,o,k] * Y[b,k,p] ------------
// grid = 8 b * 36 px-tiles(256) * 2 o-groups(128) = 576 blocks, 256 thr
__global__ __launch_bounds__(256) void mix_kernel(const float* __restrict__ Y,
                                                  const float* __restrict__ affw,
                                                  float* __restrict__ out) {
    const int bi = blockIdx.x;   // 576
    const int b = bi / 72;
    const int rem = bi % 72;
    const int ptile = rem % 36;
    const int og = rem / 36;     // 0..1
    const int px = ptile * 256 + threadIdx.x;

    float y[C8];
    #pragma unroll
    for (int k = 0; k < C8; ++k)
        y[k] = Y[((size_t)(b * C8 + k)) * HW + px];

    const float* __restrict__ ab = affw + (size_t)b * C * C8;
    const int o0 = og * 128;
    for (int o = o0; o < o0 + 128; ++o) {
        const float* ar = ab + o * C8;   // wave-uniform -> s_load
        float acc = 0.f;
        #pragma unroll
        for (int k = 0; k < C8; ++k) acc += ar[k] * y[k];
        out[((size_t)b * C + o) * HW + px] = acc;
    }
}

extern "C" void kernel_launch(void* const* d_in, const int* in_sizes, int n_in,
                              void* d_out, int out_size, void* d_ws, size_t ws_size,
                              hipStream_t stream) {
    const float* x1  = (const float*)d_in[0];
    const float* x   = (const float*)d_in[1];
    const float* wq  = (const float*)d_in[2];
    const float* bq  = (const float*)d_in[3];
    const float* wk  = (const float*)d_in[4];
    const float* bk  = (const float*)d_in[5];
    const float* con = (const float*)d_in[6];
    float* out = (float*)d_out;

    float* ws    = (float*)d_ws;
    float* px1   = ws;                          // B*C*280   = 573440
    float* px    = ws + 573440;                 // 573440
    float* PQ    = ws + 1146880;                // 573440
    float* PK    = ws + 1720320;                // 71680
    float* affw  = ws + 1792000;                // 65536
    unsigned short* aswz = (unsigned short*)(ws + 1857536);  // 73728 bf16 = 36864 floats
    float* Y     = ws + 1894400;                // 8*32*9216 = 2359296  (total ~17 MB)

    aswz_kernel<<<288, 256, 0, stream>>>(con, aswz);
    pool_kernel<<<4096, 256, 0, stream>>>(x1, x, px1, px);
    proj_kernel<<<B * 72, 320, 0, stream>>>(px1, px, wq, bq, wk, bk, PQ, PK);
    aff_kernel<<<B * 32, 256, 0, stream>>>(PQ, PK, affw);
    yconv_mfma<<<256, 192, 0, stream>>>(x1, aswz, Y);
    mix_kernel<<<576, 256, 0, stream>>>(Y, affw, out);
}

// Round 4
// 419.817 us; speedup vs baseline: 1.7435x; 1.3390x over previous
//
#include <hip/hip_runtime.h>
#include <hip/hip_bf16.h>

// Problem: B=8, C=256, H=W=96, c8=32, pool sizes {1,3,5,7,14} -> 280 positions.
// Restructured: out[b,o] = sum_k aff[b,o,k] * conv3x3(x_1[b], con[k])
//               psp(wq@x+bq) = wq@psp(x)+bq  (pool rows sum to 1)
// yconv as implicit-GEMM bf16 MFMA on channel-last bf16 x_1, K split over 4 blocks.

#define B 8
#define C 256
#define C8 32
#define H 96
#define W 96
#define HW 9216
#define NPOS 280
#define NWBIN 30

typedef __attribute__((ext_vector_type(8))) short short8;
typedef __attribute__((ext_vector_type(4))) float float4v;

static __device__ __forceinline__ unsigned short f2bf(float f) {
    unsigned u = __float_as_uint(f);
    unsigned r = (u + 0x7FFF + ((u >> 16) & 1)) >> 16;   // RNE
    return (unsigned short)r;
}
static __device__ __forceinline__ float bf2f(unsigned short h) {
    unsigned u = ((unsigned)h) << 16;
    return __uint_as_float(u);
}

// ---------------- pooling: [B,C,96,96] -> [B,C,280] for both x_1 and x ----
__global__ __launch_bounds__(256) void pool_kernel(const float* __restrict__ x1,
                                                   const float* __restrict__ x,
                                                   float* __restrict__ px1,
                                                   float* __restrict__ px) {
    __shared__ float plane[96 * 97];
    __shared__ float rowp[NWBIN * 97];
    const int bi = blockIdx.x;           // 0..4095
    const int which = bi >> 11;          // 0: x_1, 1: x
    const int bc = bi & 2047;
    const float* __restrict__ src = (which ? x : x1) + (size_t)bc * HW;
    float* __restrict__ dst = (which ? px : px1) + (size_t)bc * NPOS;
    const int tid = threadIdx.x;

    const float4* __restrict__ src4 = (const float4*)src;
    for (int idx = tid; idx < HW / 4; idx += 256) {
        float4 v = src4[idx];
        int h = idx / 24;
        int w = (idx - h * 24) * 4;
        plane[h * 97 + w + 0] = v.x;
        plane[h * 97 + w + 1] = v.y;
        plane[h * 97 + w + 2] = v.z;
        plane[h * 97 + w + 3] = v.w;
    }
    __syncthreads();

    const int SC[5]   = {1, 3, 5, 7, 14};
    const int WOFF[5] = {0, 1, 4, 9, 16};
    const int POFF[5] = {0, 1, 10, 35, 84};

    for (int task = tid; task < NWBIN * 96; task += 256) {
        int bin = task / 96;
        int h = task - bin * 96;
        int si;
        if (bin < 1) si = 0; else if (bin < 4) si = 1; else if (bin < 9) si = 2;
        else if (bin < 16) si = 3; else si = 4;
        int s = SC[si];
        int j = bin - WOFF[si];
        int st = (j * 96) / s;
        int en = (96 * (j + 1) + s - 1) / s;
        float sum = 0.f;
        for (int w = st; w < en; ++w) sum += plane[h * 97 + w];
        rowp[bin * 97 + h] = sum * (1.0f / (float)(en - st));
    }
    __syncthreads();

    for (int p = tid; p < NPOS; p += 256) {
        int si;
        if (p < 1) si = 0; else if (p < 10) si = 1; else if (p < 35) si = 2;
        else if (p < 84) si = 3; else si = 4;
        int s = SC[si];
        int loc = p - POFF[si];
        int i = loc / s;
        int j = loc - i * s;
        int st = (i * 96) / s;
        int en = (96 * (i + 1) + s - 1) / s;
        int binrow = WOFF[si] + j;
        float sum = 0.f;
        for (int h = st; h < en; ++h) sum += rowp[binrow * 97 + h];
        dst[p] = sum * (1.0f / (float)(en - st));
    }
}

// ---------------- proj: PQ = wq@px1+bq [B,256,280]; PK = wk@px+bk [B,32,280]
__global__ __launch_bounds__(320) void proj_kernel(const float* __restrict__ px1,
                                                   const float* __restrict__ px,
                                                   const float* __restrict__ wq,
                                                   const float* __restrict__ bq,
                                                   const float* __restrict__ wk,
                                                   const float* __restrict__ bk,
                                                   float* __restrict__ PQ,
                                                   float* __restrict__ PK) {
    const int bi = blockIdx.x;   // B * 72
    const int b = bi / 72;
    const int r = bi % 72;
    const int tid = threadIdx.x;
    const float* src;
    const float* wm;
    const float* bias;
    float* dst;
    int o0;
    if (r < 64) {
        o0 = r * 4;
        src = px1 + (size_t)b * C * NPOS;
        wm = wq; bias = bq;
        dst = PQ + ((size_t)b * C + o0) * NPOS;
    } else {
        o0 = (r - 64) * 4;
        src = px + (size_t)b * C * NPOS;
        wm = wk; bias = bk;
        dst = PK + ((size_t)b * C8 + o0) * NPOS;
    }
    if (tid >= NPOS) return;
    float a0 = 0.f, a1 = 0.f, a2 = 0.f, a3 = 0.f;
    for (int c = 0; c < C; ++c) {
        float xv = src[c * NPOS + tid];
        a0 += wm[(o0 + 0) * C + c] * xv;
        a1 += wm[(o0 + 1) * C + c] * xv;
        a2 += wm[(o0 + 2) * C + c] * xv;
        a3 += wm[(o0 + 3) * C + c] * xv;
    }
    dst[0 * NPOS + tid] = a0 + bias[o0 + 0];
    dst[1 * NPOS + tid] = a1 + bias[o0 + 1];
    dst[2 * NPOS + tid] = a2 + bias[o0 + 2];
    dst[3 * NPOS + tid] = a3 + bias[o0 + 3];
}

// ---------------- aff[b,o,k] = sigmoid(PQ[b,o,:] . PK[b,k,:]) --------------
__global__ __launch_bounds__(256) void aff_kernel(const float* __restrict__ PQ,
                                                  const float* __restrict__ PK,
                                                  float* __restrict__ affw) {
    __shared__ float pk[NPOS];
    const int b = blockIdx.x >> 5;
    const int k = blockIdx.x & 31;
    const int tid = threadIdx.x;
    const float* __restrict__ pkr = PK + ((size_t)b * C8 + k) * NPOS;
    if (tid < 256) pk[tid] = pkr[tid];
    if (tid < NPOS - 256) pk[tid + 256] = pkr[tid + 256];
    __syncthreads();
    const float4* __restrict__ q4 = (const float4*)(PQ + ((size_t)b * C + tid) * NPOS);
    const float4* __restrict__ p4 = (const float4*)pk;
    float acc = 0.f;
    #pragma unroll 10
    for (int i = 0; i < NPOS / 4; ++i) {
        float4 a = q4[i];
        float4 c = p4[i];
        acc += a.x * c.x + a.y * c.y + a.z * c.z + a.w * c.w;
    }
    float s = 1.0f / (1.0f + __expf(-acc));
    affw[((size_t)b * C + tid) * C8 + k] = s;
}

// ---------------- prep: con[k,c,3,3] -> Aswz in MFMA A-fragment order ------
// Aswz[((s*2 + mt)*64 + lane)*8 + j], s = pos*8+cg:
//   A[m=lane&15][k=(lane>>4)*8+j],  m -> k_out = mt*16+m, k -> c = cg*32+k
__global__ __launch_bounds__(256) void aswz_kernel(const float* __restrict__ con,
                                                   unsigned short* __restrict__ aswz) {
    int idx = blockIdx.x * 256 + threadIdx.x;   // 72*2*64*8 = 73728
    if (idx >= 73728) return;
    int j = idx & 7;
    int lane = (idx >> 3) & 63;
    int mt = (idx >> 9) & 1;
    int s = idx >> 10;          // 0..71
    int pos = s >> 3;
    int cg = s & 7;
    int m = lane & 15, quad = lane >> 4;
    int ko = mt * 16 + m;
    int c = cg * 32 + quad * 8 + j;
    int dy = pos / 3, dx = pos - dy * 3;
    float v = con[((ko * C + c) * 3 + dy) * 3 + dx];
    aswz[idx] = f2bf(v);
}

// ---------------- transpose x1[b,c,pix] f32 -> xbf[b,pix,c] bf16 -----------
// 64 ch x 64 pix tiles. grid = 8 * 144 * 4 = 4608 blocks, 256 thr.
__global__ __launch_bounds__(256) void x2bf_kernel(const float* __restrict__ x1,
                                                   unsigned short* __restrict__ xbf) {
    __shared__ unsigned short tl[64 * 65];
    const int bi = blockIdx.x;
    const int b = bi / 576;
    const int rem = bi % 576;
    const int pt = rem >> 2;
    const int ct = rem & 3;
    const int p0 = pt * 64, c0 = ct * 64;
    const int wid = threadIdx.x >> 6;
    const int lane = threadIdx.x & 63;

    #pragma unroll
    for (int it = 0; it < 16; ++it) {
        int r = it * 4 + wid;   // channel within tile
        tl[r * 65 + lane] = f2bf(x1[((size_t)(b * C + c0 + r)) * HW + p0 + lane]);
    }
    __syncthreads();
    #pragma unroll
    for (int it = 0; it < 16; ++it) {
        int pr = it * 4 + wid;  // pixel within tile
        xbf[((size_t)b * HW + p0 + pr) * 256 + c0 + lane] = tl[lane * 65 + pr];
    }
}

// ---------------- Y = W @ im2col(x1) via MFMA, K split over 4 blocks -------
// tile 8 rows x 48 cols = 384 px = 24 N-tiles; 4 waves x 6 N-tiles.
// grid = 4 kchunk * 2 xtiles * 12 ytiles * 8 b = 768 blocks (3/CU, 12 waves/CU)
__global__ __launch_bounds__(256) void yconv_mfma(const unsigned short* __restrict__ xbf,
                                                  const unsigned short* __restrict__ aswz,
                                                  unsigned short* __restrict__ Yp) {
    __shared__ unsigned short xsl[10 * 50 * 40];   // [row][col][ch pad 40] = 40000 B
    const int bi = blockIdx.x;
    const int kc = bi & 3;
    const int rest = bi >> 2;          // 0..191
    const int tilex = rest & 1;
    const int tiley = (rest >> 1) % 12;
    const int b = rest / 24;
    const int tid = threadIdx.x;
    const int wid = tid >> 6;
    const int lane = tid & 63;
    const int n = lane & 15, quad = lane >> 4;

    float4v acc[2][6];
    #pragma unroll
    for (int mt = 0; mt < 2; ++mt)
        #pragma unroll
        for (int t = 0; t < 6; ++t)
            acc[mt][t] = (float4v){0.f, 0.f, 0.f, 0.f};

    int baseb[6];
    #pragma unroll
    for (int t = 0; t < 6; ++t) {
        int tt = wid * 6 + t;
        int rt = tt / 3;
        int xb = (tt % 3) * 16;
        baseb[t] = (rt * 50 + xb + n) * 40 + quad * 8;
    }

    for (int ci = 0; ci < 2; ++ci) {
        const int cg = kc * 2 + ci;
        __syncthreads();
        // stage X slab: 10 rows x 50 cols x 32 ch bf16, pure uint4 copies
        for (int task = tid; task < 2000; task += 256) {
            int pix = task >> 2;       // 0..499
            int cq = task & 3;
            int r = pix / 50;
            int col = pix - r * 50;
            int gy = tiley * 8 + r - 1;
            int gx = tilex * 48 + col - 1;
            uint4 v = make_uint4(0u, 0u, 0u, 0u);
            if ((unsigned)gy < 96u && (unsigned)gx < 96u)
                v = *(const uint4*)&xbf[((size_t)b * HW + gy * 96 + gx) * 256 + cg * 32 + cq * 8];
            *(uint4*)&xsl[(r * 50 + col) * 40 + cq * 8] = v;
        }
        // A-fragments straight from global (L2-hot, 18 x 16B per lane)
        short8 af[9][2];
        #pragma unroll
        for (int pos = 0; pos < 9; ++pos)
            #pragma unroll
            for (int mt = 0; mt < 2; ++mt)
                af[pos][mt] = *(const short8*)&aswz[((((pos * 8 + cg) * 2) + mt) * 64 + lane) * 8];
        __syncthreads();

        #pragma unroll
        for (int pos = 0; pos < 9; ++pos) {
            const int dy = pos / 3, dx = pos - (pos / 3) * 3;
            const int d = (dy * 50 + dx) * 40;
            #pragma unroll
            for (int t = 0; t < 6; ++t) {
                short8 bf = *(const short8*)&xsl[baseb[t] + d];
                acc[0][t] = __builtin_amdgcn_mfma_f32_16x16x32_bf16(af[pos][0], bf, acc[0][t], 0, 0, 0);
                acc[1][t] = __builtin_amdgcn_mfma_f32_16x16x32_bf16(af[pos][1], bf, acc[1][t], 0, 0, 0);
            }
        }
    }

    // store partial (bf16): D col=lane&15 -> pixel, row=quad*4+reg -> k_out
    #pragma unroll
    for (int mt = 0; mt < 2; ++mt) {
        #pragma unroll
        for (int t = 0; t < 6; ++t) {
            int tt = wid * 6 + t;
            int rt = tt / 3;
            int xb = (tt % 3) * 16;
            int gy = tiley * 8 + rt;
            int gx = tilex * 48 + xb + n;
            #pragma unroll
            for (int reg = 0; reg < 4; ++reg) {
                int ko = mt * 16 + quad * 4 + reg;
                Yp[(((size_t)kc * B + b) * C8 + ko) * HW + gy * 96 + gx] = f2bf(acc[mt][t][reg]);
            }
        }
    }
}

// ---------------- mix: out[b,o,p] = sum_k aff[b,o,k] * sum_kc Yp -----------
// grid = 8 b * 36 px-tiles(256) * 4 o-groups(64) = 1152 blocks, 256 thr
__global__ __launch_bounds__(256) void mix_kernel(const unsigned short* __restrict__ Yp,
                                                  const float* __restrict__ affw,
                                                  float* __restrict__ out) {
    const int bi = blockIdx.x;   // 1152
    const int b = bi / 144;
    const int rem = bi % 144;
    const int ptile = rem % 36;
    const int og = rem / 36;     // 0..3
    const int px = ptile * 256 + threadIdx.x;

    float y[C8];
    #pragma unroll
    for (int k = 0; k < C8; ++k) y[k] = 0.f;
    #pragma unroll
    for (int kc = 0; kc < 4; ++kc) {
        #pragma unroll
        for (int k = 0; k < C8; ++k)
            y[k] += bf2f(Yp[(((size_t)kc * B + b) * C8 + k) * HW + px]);
    }

    const float* __restrict__ ab = affw + (size_t)b * C * C8;
    const int o0 = og * 64;
    for (int o = o0; o < o0 + 64; ++o) {
        const float* ar = ab + o * C8;   // wave-uniform -> s_load
        float acc = 0.f;
        #pragma unroll
        for (int k = 0; k < C8; ++k) acc += ar[k] * y[k];
        out[((size_t)b * C + o) * HW + px] = acc;
    }
}

extern "C" void kernel_launch(void* const* d_in, const int* in_sizes, int n_in,
                              void* d_out, int out_size, void* d_ws, size_t ws_size,
                              hipStream_t stream) {
    const float* x1  = (const float*)d_in[0];
    const float* x   = (const float*)d_in[1];
    const float* wq  = (const float*)d_in[2];
    const float* bq  = (const float*)d_in[3];
    const float* wk  = (const float*)d_in[4];
    const float* bk  = (const float*)d_in[5];
    const float* con = (const float*)d_in[6];
    float* out = (float*)d_out;

    float* ws = (float*)d_ws;
    // persistent across whole launch:
    float* affw          = ws;                              // 65536 f
    unsigned short* aswz = (unsigned short*)(ws + 65536);   // 73728 bf16 = 36864 f
    // pool/proj scratch (dead after aff_kernel):
    float* px1 = ws + 102400;                               // 573440 f
    float* px  = ws + 675840;                               // 573440 f
    float* PQ  = ws + 1249280;                              // 573440 f
    float* PK  = ws + 1822720;                              // 71680 f  -> end 1894400
    // xbf ALIASES the pool/proj scratch (x2bf launches after aff_kernel):
    unsigned short* xbf = (unsigned short*)(ws + 102400);   // 8*9216*256 bf16 = 9437184 f
    unsigned short* Yp  = (unsigned short*)(ws + 9539584);  // 4*8*32*9216 bf16 = 4718592 f
    // total: 14258176 floats = 57.0 MB

    aswz_kernel<<<288, 256, 0, stream>>>(con, aswz);
    pool_kernel<<<4096, 256, 0, stream>>>(x1, x, px1, px);
    proj_kernel<<<B * 72, 320, 0, stream>>>(px1, px, wq, bq, wk, bk, PQ, PK);
    aff_kernel<<<B * 32, 256, 0, stream>>>(PQ, PK, affw);
    x2bf_kernel<<<4608, 256, 0, stream>>>(x1, xbf);         // after aff: aliasing safe
    yconv_mfma<<<768, 256, 0, stream>>>(xbf, aswz, Yp);
    mix_kernel<<<1152, 256, 0, stream>>>(Yp, affw, out);
}